// Round 3
// baseline (602.561 us; speedup 1.0000x reference)
//
#include <hip/hip_runtime.h>

typedef unsigned short ushort_t;
typedef unsigned int uint_t;
typedef __attribute__((ext_vector_type(8))) _Float16 half8;
typedef __attribute__((ext_vector_type(4))) float f32x4;

#define MFMA16 __builtin_amdgcn_mfma_f32_16x16x32_f16

__device__ __forceinline__ ushort_t f2h(float f) {
  union { _Float16 h; ushort_t u; } c;
  c.h = (_Float16)f;            // v_cvt_f16_f32, RNE
  return c.u;
}
__device__ __forceinline__ float h2f(ushort_t u) {
  union { _Float16 h; ushort_t u; } c;
  c.u = u;
  return (float)c.h;
}
__device__ __forceinline__ float sigmoid_f(float x) {
  return 1.0f / (1.0f + __expf(-x));
}
__device__ __forceinline__ float tanh_f(float x) {
  float e = __expf(2.0f * x);          // saturates correctly at +-inf
  return 1.0f - 2.0f / (e + 1.0f);
}

union U8 { half8 h; _Float16 f[8]; ushort_t u[8]; };

// ---------------------------------------------------------------------------
// Pre-pass: WT[c][k] = Wcat[k][c] as fp16.  WT is [1024][512], rows:
//   c   0..255 : z  (k<256: W_z1[k][c],  k>=256: W_z2[k-256][c])
//   c 256..511 : r  (W_r1 / W_r2)
//   c 512..767 : t1 (k<256: W_h1[k][c];  k>=256 never read)
//   c 768..1023: t2 (k>=256: W_h2[k-256][c]; k<256 never read)
// ---------------------------------------------------------------------------
__global__ __launch_bounds__(256) void wtrans_kernel(
    const float* __restrict__ s0, const float* __restrict__ s1,
    const float* __restrict__ s2, const float* __restrict__ s3,
    const float* __restrict__ s4, const float* __restrict__ s5,
    ushort_t* __restrict__ WT)
{
  __shared__ float t[32][33];
  const float* Ss[6] = {s0, s1, s2, s3, s4, s5};
  const int cOffA[6] = {0, 0, 256, 256, 512, 768};
  const int kOffA[6] = {0, 256, 0, 256, 0, 256};
  int mi = blockIdx.z;
  const float* S = Ss[mi];
  int c0 = blockIdx.x * 32, k0 = blockIdx.y * 32;
  int tx = threadIdx.x, ty = threadIdx.y;   // 32 x 8
#pragma unroll
  for (int j = 0; j < 4; ++j)
    t[ty + 8 * j][tx] = S[(size_t)(k0 + ty + 8 * j) * 256 + c0 + tx];
  __syncthreads();
#pragma unroll
  for (int j = 0; j < 4; ++j) {
    int crel = ty + 8 * j;
    WT[(size_t)(cOffA[mi] + c0 + crel) * 512 + (kOffA[mi] + k0 + tx)] =
        f2h(t[tx][crel]);
  }
}

// ---------------------------------------------------------------------------
// Main fused kernel: one block per batch. 8 waves (512 threads).
// Phase A: sAXH = fp16(A @ [X | hidden])  (128 x 512, XOR-swizzled LDS)
// Gate phase (barrier-free): z,r interleaved K-sweep; t2-sweep; fold r*t2;
// t1-sweep; elementwise epilogue + store.
// ---------------------------------------------------------------------------
__global__ __launch_bounds__(512, 2) void grugnn_kernel(
    const float* __restrict__ X, const float* __restrict__ A,
    const float* __restrict__ Hin,
    const float* __restrict__ bz, const float* __restrict__ br,
    const float* __restrict__ bh,
    const ushort_t* __restrict__ WT, float* __restrict__ out)
{
  __shared__ ushort_t sAXH[128 * 512];   // 128 KiB, swizzle: idx ^ ((row&7)<<3)

  int b = blockIdx.x;
  int tid = threadIdx.x;
  int w = tid >> 6, lane = tid & 63;
  int l15 = lane & 15, l4 = lane >> 4;

  const float* Ab = A + (size_t)b * 128 * 128;
  const float* Xb = X + (size_t)b * 128 * 256;
  const float* Hb = Hin + (size_t)b * 128 * 256;
  float* Ob = out + (size_t)b * 128 * 256;

  // ---------------- Phase A ----------------
  {
    int wrow = (w >> 2) * 64;            // 0 or 64
    int wcolg = (w & 3) * 128;           // XH col base 0..383
    const float* Bsrc = (((w & 3) >= 2) ? Hb : Xb) + (w & 1) * 128;

    f32x4 acc[4][8];
#pragma unroll
    for (int mf = 0; mf < 4; ++mf)
#pragma unroll
      for (int nf = 0; nf < 8; ++nf) acc[mf][nf] = (f32x4){0.f, 0.f, 0.f, 0.f};

#pragma unroll 1
    for (int kc = 0; kc < 4; ++kc) {
      int kbase = kc * 32 + l4 * 8;
      U8 af[4];
#pragma unroll
      for (int mf = 0; mf < 4; ++mf) {
        const float* p = &Ab[(size_t)(wrow + mf * 16 + l15) * 128 + kbase];
        f32x4 v0 = *(const f32x4*)p;
        f32x4 v1 = *(const f32x4*)(p + 4);
#pragma unroll
        for (int i = 0; i < 4; ++i) {
          af[mf].f[i] = (_Float16)v0[i];
          af[mf].f[4 + i] = (_Float16)v1[i];
        }
      }
#pragma unroll
      for (int nf = 0; nf < 8; ++nf) {
        int col = nf * 16 + l15;
        U8 bf;
#pragma unroll
        for (int j = 0; j < 8; ++j)
          bf.f[j] = (_Float16)Bsrc[(size_t)(kbase + j) * 256 + col];
#pragma unroll
        for (int mf = 0; mf < 4; ++mf)
          acc[mf][nf] = MFMA16(af[mf].h, bf.h, acc[mf][nf], 0, 0, 0);
      }
    }
    // write AXH -> LDS (fp16, swizzled). C-frag: row=(l>>4)*4+reg, col=l&15.
#pragma unroll
    for (int mf = 0; mf < 4; ++mf)
#pragma unroll
      for (int nf = 0; nf < 8; ++nf)
#pragma unroll
        for (int r = 0; r < 4; ++r) {
          int row = wrow + mf * 16 + l4 * 4 + r;
          int col = wcolg + nf * 16 + l15;
          int idx = (row * 512 + col) ^ ((row & 7) << 3);
          sAXH[idx] = f2h(acc[mf][nf][r]);
        }
  }
  __syncthreads();   // the only barrier: gate phase reads sAXH only.

  // ---------------- Gate phase ----------------
  int cw = w * 32;   // this wave's 32 gate-columns (same cols for all gates)

  // --- z & r interleaved sweep (shared A-fragments), K = 0..511 ---
  f32x4 zacc[8][2], racc[8][2];
#pragma unroll
  for (int mf = 0; mf < 8; ++mf)
#pragma unroll
    for (int nf = 0; nf < 2; ++nf) {
      zacc[mf][nf] = (f32x4){0.f, 0.f, 0.f, 0.f};
      racc[mf][nf] = (f32x4){0.f, 0.f, 0.f, 0.f};
    }
#pragma unroll 1
  for (int kc = 0; kc < 16; ++kc) {
    int kk = kc * 32 + l4 * 8;
    half8 a8[8];
#pragma unroll
    for (int mf = 0; mf < 8; ++mf) {
      int row = mf * 16 + l15;
      int idx = (row * 512 + kk) ^ ((row & 7) << 3);
      a8[mf] = *(const half8*)&sAXH[idx];
    }
#pragma unroll
    for (int nf = 0; nf < 2; ++nf) {
      int c = cw + nf * 16 + l15;
      half8 bz8 = *(const half8*)&WT[(size_t)c * 512 + kk];
      half8 br8 = *(const half8*)&WT[(size_t)(256 + c) * 512 + kk];
#pragma unroll
      for (int mf = 0; mf < 8; ++mf) {
        zacc[mf][nf] = MFMA16(a8[mf], bz8, zacc[mf][nf], 0, 0, 0);
        racc[mf][nf] = MFMA16(a8[mf], br8, racc[mf][nf], 0, 0, 0);
      }
    }
  }

  // bias + sigmoid, pack z,r to fp16 pairs (frees 128 VGPRs)
  uint_t zpk[8][2][2], rpk[8][2][2];
#pragma unroll
  for (int mf = 0; mf < 8; ++mf)
#pragma unroll
    for (int nf = 0; nf < 2; ++nf) {
      int c = cw + nf * 16 + l15;
      int row0 = mf * 16 + l4 * 4;
      float zv[4], rv[4];
#pragma unroll
      for (int r = 0; r < 4; ++r) {
        zv[r] = sigmoid_f(zacc[mf][nf][r] + bz[(row0 + r) * 256 + c]);
        rv[r] = sigmoid_f(racc[mf][nf][r] + br[(row0 + r) * 256 + c]);
      }
      zpk[mf][nf][0] = (uint_t)f2h(zv[0]) | ((uint_t)f2h(zv[1]) << 16);
      zpk[mf][nf][1] = (uint_t)f2h(zv[2]) | ((uint_t)f2h(zv[3]) << 16);
      rpk[mf][nf][0] = (uint_t)f2h(rv[0]) | ((uint_t)f2h(rv[1]) << 16);
      rpk[mf][nf][1] = (uint_t)f2h(rv[2]) | ((uint_t)f2h(rv[3]) << 16);
    }

  // --- t2 = AH @ W_h2 sweep, K = 256..511 ---
  f32x4 tacc[8][2];
#pragma unroll
  for (int mf = 0; mf < 8; ++mf)
#pragma unroll
    for (int nf = 0; nf < 2; ++nf) tacc[mf][nf] = (f32x4){0.f, 0.f, 0.f, 0.f};
#pragma unroll 1
  for (int kc = 8; kc < 16; ++kc) {
    int kk = kc * 32 + l4 * 8;
    half8 a8[8];
#pragma unroll
    for (int mf = 0; mf < 8; ++mf) {
      int row = mf * 16 + l15;
      int idx = (row * 512 + kk) ^ ((row & 7) << 3);
      a8[mf] = *(const half8*)&sAXH[idx];
    }
#pragma unroll
    for (int nf = 0; nf < 2; ++nf) {
      int c = cw + nf * 16 + l15;
      half8 b8 = *(const half8*)&WT[(size_t)(768 + c) * 512 + kk];
#pragma unroll
      for (int mf = 0; mf < 8; ++mf)
        tacc[mf][nf] = MFMA16(a8[mf], b8, tacc[mf][nf], 0, 0, 0);
    }
  }
  // fold: tacc <- r * t2   (frees rpk)
#pragma unroll
  for (int mf = 0; mf < 8; ++mf)
#pragma unroll
    for (int nf = 0; nf < 2; ++nf)
#pragma unroll
      for (int r = 0; r < 4; ++r) {
        float rv = h2f((ushort_t)(rpk[mf][nf][r >> 1] >> ((r & 1) * 16)));
        tacc[mf][nf][r] *= rv;
      }

  // --- t1 = AX @ W_h1 sweep, K = 0..255 ---
  f32x4 uacc[8][2];
#pragma unroll
  for (int mf = 0; mf < 8; ++mf)
#pragma unroll
    for (int nf = 0; nf < 2; ++nf) uacc[mf][nf] = (f32x4){0.f, 0.f, 0.f, 0.f};
#pragma unroll 1
  for (int kc = 0; kc < 8; ++kc) {
    int kk = kc * 32 + l4 * 8;
    half8 a8[8];
#pragma unroll
    for (int mf = 0; mf < 8; ++mf) {
      int row = mf * 16 + l15;
      int idx = (row * 512 + kk) ^ ((row & 7) << 3);
      a8[mf] = *(const half8*)&sAXH[idx];
    }
#pragma unroll
    for (int nf = 0; nf < 2; ++nf) {
      int c = cw + nf * 16 + l15;
      half8 b8 = *(const half8*)&WT[(size_t)(512 + c) * 512 + kk];
#pragma unroll
      for (int mf = 0; mf < 8; ++mf)
        uacc[mf][nf] = MFMA16(a8[mf], b8, uacc[mf][nf], 0, 0, 0);
    }
  }

  // --- epilogue: hv = tanh(t1 + r*t2 + bias_h); h = z*hidden + (1-z)*hv ---
#pragma unroll
  for (int mf = 0; mf < 8; ++mf)
#pragma unroll
    for (int nf = 0; nf < 2; ++nf) {
      int c = cw + nf * 16 + l15;
      int row0 = mf * 16 + l4 * 4;
#pragma unroll
      for (int r = 0; r < 4; ++r) {
        int row = row0 + r;
        float pre = uacc[mf][nf][r] + tacc[mf][nf][r] + bh[row * 256 + c];
        float hv = tanh_f(pre);
        float zv = h2f((ushort_t)(zpk[mf][nf][r >> 1] >> ((r & 1) * 16)));
        float hid = Hb[row * 256 + c];
        Ob[row * 256 + c] = hv + zv * (hid - hv);
      }
    }
}

// ---------------------------------------------------------------------------
extern "C" void kernel_launch(void* const* d_in, const int* in_sizes, int n_in,
                              void* d_out, int out_size, void* d_ws, size_t ws_size,
                              hipStream_t stream)
{
  const float* X   = (const float*)d_in[0];
  const float* A   = (const float*)d_in[1];
  const float* Hid = (const float*)d_in[2];
  const float* Wz1 = (const float*)d_in[3];
  const float* Wz2 = (const float*)d_in[4];
  const float* Wr1 = (const float*)d_in[5];
  const float* Wr2 = (const float*)d_in[6];
  const float* Wh1 = (const float*)d_in[7];
  const float* Wh2 = (const float*)d_in[8];
  const float* bz  = (const float*)d_in[9];
  const float* br  = (const float*)d_in[10];
  const float* bh  = (const float*)d_in[11];
  float* out = (float*)d_out;
  ushort_t* WT = (ushort_t*)d_ws;   // needs 1024*512*2 = 1 MiB of workspace

  hipLaunchKernelGGL(wtrans_kernel, dim3(8, 8, 6), dim3(32, 8), 0, stream,
                     Wz1, Wz2, Wr1, Wr2, Wh1, Wh2, WT);
  hipLaunchKernelGGL(grugnn_kernel, dim3(512), dim3(512), 0, stream,
                     X, A, Hid, bz, br, bh, WT, out);
}